// Round 10
// baseline (1021.428 us; speedup 1.0000x reference)
//
#include <hip/hip_runtime.h>

// Problem constants
#define Bq 1024
#define Tq 512
#define Fq 64    // input features
#define Hq 128   // hidden

typedef _Float16 f16;
typedef f16 f16x2 __attribute__((ext_vector_type(2)));
typedef f16 f16x4 __attribute__((ext_vector_type(4)));
typedef f16 f16x8 __attribute__((ext_vector_type(8)));
typedef float f32x4 __attribute__((ext_vector_type(4)));

__device__ __forceinline__ float sigmoidf_(float x) {
    return 1.f / (1.f + __expf(-x));
}
__device__ __forceinline__ float tanhf_(float x) {
    return 1.f - 2.f / (__expf(2.f * x) + 1.f);
}

// ---------------- kernel A: decoder fold (one-time, tiny) ----------------
// W_comb = W_ih_dec @ W_out + W_hh_dec   (f16, [512][128])
// b_fold = b_ih_dec + b_hh_dec + W_ih_dec @ b_out   (f32, [512])
__global__ __launch_bounds__(256) void fold_kernel(
    const float* __restrict__ Wih_d, const float* __restrict__ Whh_d,
    const float* __restrict__ bih_d, const float* __restrict__ bhh_d,
    const float* __restrict__ Wout, const float* __restrict__ bout,
    f16* __restrict__ Wcomb, float* __restrict__ bfold)
{
    const int gid = blockIdx.x * 256 + threadIdx.x;   // 0..32767
    const int og = gid >> 6;          // gate row 0..511
    const int oh = (gid & 63) * 2;    // hh pair
    float ax = Whh_d[(size_t)og * Hq + oh];
    float ay = Whh_d[(size_t)og * Hq + oh + 1];
    for (int f = 0; f < Fq; ++f) {
        float w = Wih_d[(size_t)og * Fq + f];
        float2 o = *(const float2*)(Wout + (size_t)f * Hq + oh);
        ax += w * o.x; ay += w * o.y;
    }
    f16x2 r; r.x = (f16)ax; r.y = (f16)ay;
    *(f16x2*)(Wcomb + (size_t)og * Hq + oh) = r;
    if (gid < 512) {
        float b = bih_d[gid] + bhh_d[gid];
        for (int f = 0; f < Fq; ++f)
            b += Wih_d[(size_t)gid * Fq + f] * bout[f];
        bfold[gid] = b;
    }
}

// ---------------- kernel B: main recurrence ----------------
// 256 blocks x 1024 threads (16 waves = 4/SIMD, 2x the occupancy of r9),
// 4 batch rows per block. Work split so per-CU MFMA / pointwise / staging
// totals are UNCHANGED vs round 9 — only spread across 2x waves:
//   wave w (w<8):  gate-tiles {w, 8+w}      = i,f of units 16w..16w+15
//   wave 8+w:      gate-tiles {16+w, 24+w}  = g,o of same units
// i/f/g/o of a unit spans a wave pair -> gscr bounce crosses waves via the
// step barrier (2 barriers/step). Disjoint wave roles overlap:
//   waves 0-7: pointwise (512 units, 1/lane)   waves 8-15: x staging
//   waves 12-15: decoder projection + rec_err (concurrent with pointwise)
// Decoder folded (K=128, fold pre-kernel). Frag layouts validated r4-r9.
__global__ __launch_bounds__(1024, 1)
void lstm_ae_kernel(
    const float* __restrict__ ts,
    const float* __restrict__ Wih_e, const float* __restrict__ Whh_e,
    const float* __restrict__ bih_e, const float* __restrict__ bhh_e,
    const float* __restrict__ Wout, const float* __restrict__ bout,
    const f16* __restrict__ Wcomb, const float* __restrict__ bfold,
    float* __restrict__ out)
{
    const int tid = threadIdx.x;
    const int bid = blockIdx.x;
    const int row0 = bid * 4;

    const int wv = tid >> 6;       // wave 0..15
    const int wl = wv & 7;         // unit-group 0..7 (units wl*16..wl*16+15)
    const int gh = (wv >> 3) * 2;  // first owned gate: 0 (i,f) or 2 (g,o)
    const int ln = tid & 63;
    const int n16 = ln & 15;       // MFMA N col (batch col; <4 real)
    const int kg = ln >> 4;        // k-group 0..3
    const int zr = n16 & 3;        // aliased batch row for B-fragment
    const bool act = (n16 < 4);
    const int ul = ln >> 2;        // pointwise: unit-sub 0..15
    const int cl = ln & 3;         // pointwise: batch col 0..3

    __shared__ alignas(16) f16 hT[2][4][144];        // h dbuf
    __shared__ alignas(16) f16 xS[2][4][8][76];      // x chunk dbuf
    __shared__ alignas(16) float gscr[8][4][4][16];  // 8 KB gate bounce
    __shared__ float errb[4][4];

    float c_ = 0.f;    // (pointwise threads) one unit, one batch col
    float bs[4];       // bias for that unit, gates i,f,g,o

    // ===================== encoder setup =====================
    f16x8 wf[2][6];   // A-frags [owned gate][k-tile], 48 VGPR
#pragma unroll
    for (int g = 0; g < 2; ++g) {
        const int gr = (gh + g) * 128 + wl * 16 + n16;
#pragma unroll
        for (int kt = 0; kt < 6; ++kt) {
            const int kc = kt * 32 + kg * 8;
            const float* src = (kt < 2)
                ? (Wih_e + (size_t)gr * Fq + kc)
                : (Whh_e + (size_t)gr * Hq + (kc - 64));
            float4 f0 = *(const float4*)src;
            float4 f1 = *(const float4*)(src + 4);
            f16x8 a;
            a[0] = (f16)f0.x; a[1] = (f16)f0.y; a[2] = (f16)f0.z; a[3] = (f16)f0.w;
            a[4] = (f16)f1.x; a[5] = (f16)f1.y; a[6] = (f16)f1.z; a[7] = (f16)f1.w;
            wf[g][kt] = a;
        }
    }
    if (tid < 512) {   // pointwise threads: bias for unit wv*16+ul
#pragma unroll
        for (int g = 0; g < 4; ++g)
            bs[g] = bih_e[g * 128 + wv * 16 + ul] + bhh_e[g * 128 + wv * 16 + ul];
    }
    // zero h buffer 0 (waves 0-7, act lanes)
    if (wv < 8 && act) {
        f16x4 z; z[0] = (f16)0.f; z[1] = (f16)0.f; z[2] = (f16)0.f; z[3] = (f16)0.f;
        *(f16x4*)(&hT[0][n16][wv * 16 + kg * 4]) = z;
    }
    // stage x chunk 0 (waves 8-15): thread -> (r, t8, fg)
    const int t2 = tid & 511;
    const int sr = t2 >> 7, st8 = (t2 >> 4) & 7, sfg = t2 & 15;
    if (tid >= 512) {
        float4 v = *(const float4*)(ts + (size_t)(row0 + sr) * Tq * Fq +
                                    (size_t)st8 * Fq + sfg * 4);
        f16x4 h4; h4[0] = (f16)v.x; h4[1] = (f16)v.y; h4[2] = (f16)v.z; h4[3] = (f16)v.w;
        *(f16x4*)(&xS[0][sr][st8][sfg * 4]) = h4;
    }
    __syncthreads();

    // ===================== encoder: 512 steps, 2 barriers each ===========
    float4 xpre;
    for (int t = 0; t < Tq; ++t) {
        const int buf = (t >> 3) & 1, tb = t & 7, par = t & 1;
        if (tid >= 512 && tb == 0 && t < Tq - 8) {  // prefetch next chunk
            xpre = *(const float4*)(ts + (size_t)(row0 + sr) * Tq * Fq +
                                    (size_t)(t + 8 + st8) * Fq + sfg * 4);
        }
        f16x8 bf[6];
        bf[0] = *(const f16x8*)(&xS[buf][zr][tb][kg * 8]);
        bf[1] = *(const f16x8*)(&xS[buf][zr][tb][32 + kg * 8]);
#pragma unroll
        for (int kt = 0; kt < 4; ++kt)
            bf[2 + kt] = *(const f16x8*)(&hT[par][zr][kt * 32 + kg * 8]);
        f32x4 acc[2];
#pragma unroll
        for (int g = 0; g < 2; ++g) acc[g] = (f32x4){0.f, 0.f, 0.f, 0.f};
#pragma unroll
        for (int kt = 0; kt < 6; ++kt)
#pragma unroll
            for (int g = 0; g < 2; ++g)
                acc[g] = __builtin_amdgcn_mfma_f32_16x16x32_f16(
                    wf[g][kt], bf[kt], acc[g], 0, 0, 0);
        if (act) {   // D rows kg*4+r, col n16 -> gscr[unit-grp][gate][col][unit]
#pragma unroll
            for (int g = 0; g < 2; ++g)
                *(f32x4*)(&gscr[wl][gh + g][n16][kg * 4]) = acc[g];
        }
        __syncthreads();   // all 4 gates of every unit visible
        if (tid < 512) {   // waves 0-7: one unit each
            float gi = gscr[wv][0][cl][ul] + bs[0];
            float gf = gscr[wv][1][cl][ul] + bs[1];
            float gg = gscr[wv][2][cl][ul] + bs[2];
            float go = gscr[wv][3][cl][ul] + bs[3];
            float i_ = sigmoidf_(gi);
            float f_ = sigmoidf_(gf);
            float g_ = tanhf_(gg);
            float o_ = sigmoidf_(go);
            c_ = f_ * c_ + i_ * g_;
            hT[par ^ 1][cl][wv * 16 + ul] = (f16)(o_ * tanhf_(c_));
        } else if (tb == 7 && t != Tq - 1) {  // waves 8-15: publish chunk
            f16x4 h4; h4[0] = (f16)xpre.x; h4[1] = (f16)xpre.y;
            h4[2] = (f16)xpre.z; h4[3] = (f16)xpre.w;
            *(f16x4*)(&xS[buf ^ 1][sr][st8][sfg * 4]) = h4;
        }
        __syncthreads();   // h(t+1), x chunk ready
    }

    // c_enc: pointwise thread owns unit wv*16+ul of batch row cl
    if (tid < 512) out[(size_t)(row0 + cl) * Hq + wv * 16 + ul] = c_;

    // ===================== decoder setup =====================
    f16x8 wc[2][4];   // folded weights from ws: 8 x 16B loads
#pragma unroll
    for (int g = 0; g < 2; ++g) {
        const int gr = (gh + g) * 128 + wl * 16 + n16;
#pragma unroll
        for (int kt = 0; kt < 4; ++kt)
            wc[g][kt] = *(const f16x8*)(Wcomb + (size_t)gr * Hq + kt * 32 + kg * 8);
    }
    if (tid < 512) {
#pragma unroll
        for (int g = 0; g < 4; ++g)
            bs[g] = bfold[g * 128 + wv * 16 + ul];
    }
    // proj A-frags; waves 12-15 use them (mt = wv&3 = wv-12 there)
    const int mt = wv & 3;
    f16x8 wo[4];
#pragma unroll
    for (int kt = 0; kt < 4; ++kt) {
        const float* src = Wout + (size_t)(mt * 16 + n16) * Hq + kt * 32 + kg * 8;
        float4 f0 = *(const float4*)src;
        float4 f1 = *(const float4*)(src + 4);
        f16x8 a;
        a[0] = (f16)f0.x; a[1] = (f16)f0.y; a[2] = (f16)f0.z; a[3] = (f16)f0.w;
        a[4] = (f16)f1.x; a[5] = (f16)f1.y; a[6] = (f16)f1.z; a[7] = (f16)f1.w;
        wo[kt] = a;
    }
    float4 bo4 = *(const float4*)(bout + mt * 16 + kg * 4);
    float4 tsv = *(const float4*)(ts + (size_t)(row0 + zr) * Tq * Fq +
                                  (size_t)(Tq - 1) * Fq + mt * 16 + kg * 4);
    float err_ = 0.f;
    __syncthreads();

    // ===================== decoder: 512 steps, 2 barriers each ===========
    for (int k = 0; k < Tq; ++k) {
        const int pk = k & 1;
        f16x8 bf[4];
#pragma unroll
        for (int kt = 0; kt < 4; ++kt)
            bf[kt] = *(const f16x8*)(&hT[pk][zr][kt * 32 + kg * 8]);
        f32x4 acc[2];
#pragma unroll
        for (int g = 0; g < 2; ++g) acc[g] = (f32x4){0.f, 0.f, 0.f, 0.f};
#pragma unroll
        for (int kt = 0; kt < 4; ++kt)
#pragma unroll
            for (int g = 0; g < 2; ++g)
                acc[g] = __builtin_amdgcn_mfma_f32_16x16x32_f16(
                    wc[g][kt], bf[kt], acc[g], 0, 0, 0);
        f32x4 pacc = (f32x4){0.f, 0.f, 0.f, 0.f};
        if (wv >= 12) {   // projection of h[pk] for rec_err
#pragma unroll
            for (int kt = 0; kt < 4; ++kt)
                pacc = __builtin_amdgcn_mfma_f32_16x16x32_f16(
                    wo[kt], bf[kt], pacc, 0, 0, 0);
        }
        if (act) {
#pragma unroll
            for (int g = 0; g < 2; ++g)
                *(f32x4*)(&gscr[wl][gh + g][n16][kg * 4]) = acc[g];
        }
        __syncthreads();
        if (tid < 512) {   // waves 0-7: pointwise
            float gi = gscr[wv][0][cl][ul] + bs[0];
            float gf = gscr[wv][1][cl][ul] + bs[1];
            float gg = gscr[wv][2][cl][ul] + bs[2];
            float go = gscr[wv][3][cl][ul] + bs[3];
            float i_ = sigmoidf_(gi);
            float f_ = sigmoidf_(gf);
            float g_ = tanhf_(gg);
            float o_ = sigmoidf_(go);
            c_ = f_ * c_ + i_ * g_;
            hT[pk ^ 1][cl][wv * 16 + ul] = (f16)(o_ * tanhf_(c_));
        } else if (wv >= 12 && act) {  // waves 12-15: err (overlaps pointwise)
            float a0 = pacc[0] + bo4.x, a1 = pacc[1] + bo4.y;
            float a2 = pacc[2] + bo4.z, a3 = pacc[3] + bo4.w;
            if (k == 0) {
                float4 av; av.x = a0; av.y = a1; av.z = a2; av.w = a3;
                *(float4*)(out + (size_t)Bq * Hq + Bq +
                           (size_t)(row0 + n16) * Fq + mt * 16 + kg * 4) = av;
            }
            err_ += fabsf(a0 * a0 - tsv.x * tsv.x);
            err_ += fabsf(a1 * a1 - tsv.y * tsv.y);
            err_ += fabsf(a2 * a2 - tsv.z * tsv.z);
            err_ += fabsf(a3 * a3 - tsv.w * tsv.w);
            if (k < Tq - 1)
                tsv = *(const float4*)(ts + (size_t)(row0 + n16) * Tq * Fq +
                                       (size_t)(Tq - 2 - k) * Fq +
                                       mt * 16 + kg * 4);
        }
        __syncthreads();
    }

    // rec_err reduction: waves 12-15 hold per-(row,f-slice) partials
    if (wv >= 12) {
        err_ += __shfl_xor(err_, 16, 64);   // sum over kg bit 0
        err_ += __shfl_xor(err_, 32, 64);   // sum over kg bit 1
        if (kg == 0 && act) errb[mt][n16] = err_;
    }
    __syncthreads();
    if (tid < 4) {
        float e = errb[0][tid] + errb[1][tid] + errb[2][tid] + errb[3][tid];
        out[(size_t)Bq * Hq + row0 + tid] = e;
    }
}

extern "C" void kernel_launch(void* const* d_in, const int* in_sizes, int n_in,
                              void* d_out, int out_size, void* d_ws, size_t ws_size,
                              hipStream_t stream) {
    const float* ts    = (const float*)d_in[0];
    const float* Wih_e = (const float*)d_in[1];
    const float* Whh_e = (const float*)d_in[2];
    const float* bih_e = (const float*)d_in[3];
    const float* bhh_e = (const float*)d_in[4];
    const float* Wih_d = (const float*)d_in[5];
    const float* Whh_d = (const float*)d_in[6];
    const float* bih_d = (const float*)d_in[7];
    const float* bhh_d = (const float*)d_in[8];
    const float* Wout  = (const float*)d_in[9];
    const float* bout  = (const float*)d_in[10];
    float* out = (float*)d_out;

    f16*   Wcomb = (f16*)d_ws;                                   // 128 KB
    float* bfold = (float*)((char*)d_ws + (size_t)512 * 128 * 2); // +2 KB

    hipLaunchKernelGGL(fold_kernel, dim3(128), dim3(256), 0, stream,
                       Wih_d, Whh_d, bih_d, bhh_d, Wout, bout, Wcomb, bfold);
    hipLaunchKernelGGL(lstm_ae_kernel, dim3(Bq / 4), dim3(1024), 0, stream,
                       ts, Wih_e, Whh_e, bih_e, bhh_e,
                       Wout, bout, Wcomb, bfold, out);
}

// Round 11
// 777.962 us; speedup vs baseline: 1.3130x; 1.3130x over previous
//
#include <hip/hip_runtime.h>

// Problem constants
#define Bq 1024
#define Tq 512
#define Fq 64    // input features
#define Hq 128   // hidden

typedef _Float16 f16;
typedef f16 f16x2 __attribute__((ext_vector_type(2)));
typedef f16 f16x4 __attribute__((ext_vector_type(4)));
typedef f16 f16x8 __attribute__((ext_vector_type(8)));
typedef float f32x4 __attribute__((ext_vector_type(4)));

__device__ __forceinline__ float sigmoidf_(float x) {
    return 1.f / (1.f + __expf(-x));
}
__device__ __forceinline__ float tanhf_(float x) {
    return 1.f - 2.f / (__expf(2.f * x) + 1.f);
}

// compile-time-indexed select of one element of an f32x4 (no dynamic
// vector indexing -> no scratch, rule #20): 3 cndmasks
__device__ __forceinline__ float sel4(f32x4 v, int s) {
    float r = v.x;
    r = (s == 1) ? v.y : r;
    r = (s == 2) ? v.z : r;
    r = (s == 3) ? v.w : r;
    return r;
}

// ---------------- kernel A: decoder fold (one-time, tiny) ----------------
// W_comb = W_ih_dec @ W_out + W_hh_dec   (f16, [512][128])
// b_fold = b_ih_dec + b_hh_dec + W_ih_dec @ b_out   (f32, [512])
__global__ __launch_bounds__(256) void fold_kernel(
    const float* __restrict__ Wih_d, const float* __restrict__ Whh_d,
    const float* __restrict__ bih_d, const float* __restrict__ bhh_d,
    const float* __restrict__ Wout, const float* __restrict__ bout,
    f16* __restrict__ Wcomb, float* __restrict__ bfold)
{
    const int gid = blockIdx.x * 256 + threadIdx.x;   // 0..32767
    const int og = gid >> 6;          // gate row 0..511
    const int oh = (gid & 63) * 2;    // hh pair
    float ax = Whh_d[(size_t)og * Hq + oh];
    float ay = Whh_d[(size_t)og * Hq + oh + 1];
    for (int f = 0; f < Fq; ++f) {
        float w = Wih_d[(size_t)og * Fq + f];
        float2 o = *(const float2*)(Wout + (size_t)f * Hq + oh);
        ax += w * o.x; ay += w * o.y;
    }
    f16x2 r; r.x = (f16)ax; r.y = (f16)ay;
    *(f16x2*)(Wcomb + (size_t)og * Hq + oh) = r;
    if (gid < 512) {
        float b = bih_d[gid] + bhh_d[gid];
        for (int f = 0; f < Fq; ++f)
            b += Wih_d[(size_t)gid * Fq + f] * bout[f];
        bfold[gid] = b;
    }
}

// ---------------- kernel B: main recurrence ----------------
// 256 blocks x 512 threads (8 waves), 4 batch rows per block — r9 structure
// with the gscr LDS bounce ELIMINATED: wave w owns all 4 gates of its 16
// units in D-layout (tiles {w,8+w,16+w,24+w}), so the pointwise is fully
// in-register. Lane (n16,kg) takes unit kg*4+(n16>>2), col n16&3, selecting
// acc[g][n16>>2] with 3 cndmasks per gate (12 VALU) instead of the LDS
// write -> lgkmcnt(0) -> 4 scalar reads round-trip (~250 cyc serial).
// All 64 lanes run ONE unit's nonlinearity. 1 barrier/step.
// Decoder folded (K=128, fold pre-kernel); proj+err concurrent on waves 4-7.
// Frag layouts (validated rounds 4-10):
//   A: lane l holds A[l&15][(l>>4)*8+j]   B: lane l holds B[(l>>4)*8+j][l&15]
//   D: lane l reg r = D[(l>>4)*4+r][l&15]
__global__ __launch_bounds__(512)
__attribute__((amdgpu_waves_per_eu(2)))
void lstm_ae_kernel(
    const float* __restrict__ ts,
    const float* __restrict__ Wih_e, const float* __restrict__ Whh_e,
    const float* __restrict__ bih_e, const float* __restrict__ bhh_e,
    const float* __restrict__ Wout, const float* __restrict__ bout,
    const f16* __restrict__ Wcomb, const float* __restrict__ bfold,
    float* __restrict__ out)
{
    const int tid = threadIdx.x;
    const int bid = blockIdx.x;
    const int row0 = bid * 4;

    const int wv = tid >> 6;       // wave 0..7 (owns units wv*16..wv*16+15)
    const int ln = tid & 63;
    const int n16 = ln & 15;       // MFMA N col (batch col; <4 real)
    const int kg = ln >> 4;        // k-group 0..3 (D rows kg*4..kg*4+3)
    const int zr = n16 & 3;        // batch row for B-frag AND pointwise col
    const bool act = (n16 < 4);
    const int us = n16 >> 2;       // D-reg select: this lane's unit sub-index
    const int un = kg * 4 + us;    // pointwise: unit (wv*16+un), col zr

    __shared__ alignas(16) f16 hT[2][4][144];        // h dbuf
    __shared__ alignas(16) f16 xS[2][4][8][76];      // x chunk dbuf
    __shared__ float errb[4][4];

    float c_ = 0.f;    // one unit (wv*16+un), one batch col (zr)
    float bs[4];       // bias for that unit, gates i,f,g,o

    // ===================== encoder setup =====================
    f16x8 wf[4][6];   // A-frags [gate][k-tile], 96 VGPR
#pragma unroll
    for (int g = 0; g < 4; ++g) {
        const int gr = g * 128 + wv * 16 + n16;
#pragma unroll
        for (int kt = 0; kt < 6; ++kt) {
            const int kc = kt * 32 + kg * 8;
            const float* src = (kt < 2)
                ? (Wih_e + (size_t)gr * Fq + kc)
                : (Whh_e + (size_t)gr * Hq + (kc - 64));
            float4 f0 = *(const float4*)src;
            float4 f1 = *(const float4*)(src + 4);
            f16x8 a;
            a[0] = (f16)f0.x; a[1] = (f16)f0.y; a[2] = (f16)f0.z; a[3] = (f16)f0.w;
            a[4] = (f16)f1.x; a[5] = (f16)f1.y; a[6] = (f16)f1.z; a[7] = (f16)f1.w;
            wf[g][kt] = a;
        }
        bs[g] = bih_e[g * 128 + wv * 16 + un] + bhh_e[g * 128 + wv * 16 + un];
    }

    // zero h buffer 0
    if (act) {
        f16x4 z; z[0] = (f16)0.f; z[1] = (f16)0.f; z[2] = (f16)0.f; z[3] = (f16)0.f;
        *(f16x4*)(&hT[0][n16][wv * 16 + kg * 4]) = z;
    }
    // stage x chunk 0: thread -> (r, t8, fg)
    const int sr = tid >> 7, st8 = (tid >> 4) & 7, sfg = tid & 15;
    {
        float4 v = *(const float4*)(ts + (size_t)(row0 + sr) * Tq * Fq +
                                    (size_t)st8 * Fq + sfg * 4);
        f16x4 h4; h4[0] = (f16)v.x; h4[1] = (f16)v.y; h4[2] = (f16)v.z; h4[3] = (f16)v.w;
        *(f16x4*)(&xS[0][sr][st8][sfg * 4]) = h4;
    }
    __syncthreads();

    // ===================== encoder: 512 steps, 1 barrier each ============
    float4 xpre;
    for (int t = 0; t < Tq; ++t) {
        const int buf = (t >> 3) & 1, tb = t & 7, par = t & 1;
        if (tb == 0 && t < Tq - 8) {   // issue chunk c+1 loads (hidden 8 steps)
            xpre = *(const float4*)(ts + (size_t)(row0 + sr) * Tq * Fq +
                                    (size_t)(t + 8 + st8) * Fq + sfg * 4);
        }
        f16x8 bf[6];
        bf[0] = *(const f16x8*)(&xS[buf][zr][tb][kg * 8]);
        bf[1] = *(const f16x8*)(&xS[buf][zr][tb][32 + kg * 8]);
#pragma unroll
        for (int kt = 0; kt < 4; ++kt)
            bf[2 + kt] = *(const f16x8*)(&hT[par][zr][kt * 32 + kg * 8]);
        f32x4 acc[4];
#pragma unroll
        for (int g = 0; g < 4; ++g) acc[g] = (f32x4){0.f, 0.f, 0.f, 0.f};
#pragma unroll
        for (int kt = 0; kt < 6; ++kt)
#pragma unroll
            for (int g = 0; g < 4; ++g)
                acc[g] = __builtin_amdgcn_mfma_f32_16x16x32_f16(
                    wf[g][kt], bf[kt], acc[g], 0, 0, 0);
        {   // in-register pointwise: every lane owns (unit un, col zr)
            float gi = sel4(acc[0], us) + bs[0];
            float gf = sel4(acc[1], us) + bs[1];
            float gg = sel4(acc[2], us) + bs[2];
            float go = sel4(acc[3], us) + bs[3];
            float i_ = sigmoidf_(gi);
            float f_ = sigmoidf_(gf);
            float g_ = tanhf_(gg);
            float o_ = sigmoidf_(go);
            c_ = f_ * c_ + i_ * g_;
            hT[par ^ 1][zr][wv * 16 + un] = (f16)(o_ * tanhf_(c_));
        }
        if (tb == 7 && t != Tq - 1) {  // publish staged chunk
            f16x4 h4; h4[0] = (f16)xpre.x; h4[1] = (f16)xpre.y;
            h4[2] = (f16)xpre.z; h4[3] = (f16)xpre.w;
            *(f16x4*)(&xS[buf ^ 1][sr][st8][sfg * 4]) = h4;
        }
        __syncthreads();
    }

    // c_enc: thread owns unit wv*16+un of batch row zr
    out[(size_t)(row0 + zr) * Hq + wv * 16 + un] = c_;

    // ===================== decoder setup =====================
    f16x8 wc[4][4];   // folded weights straight from ws: 16 x 16B loads
#pragma unroll
    for (int g = 0; g < 4; ++g) {
        const int gr = g * 128 + wv * 16 + n16;
#pragma unroll
        for (int kt = 0; kt < 4; ++kt)
            wc[g][kt] = *(const f16x8*)(Wcomb + (size_t)gr * Hq + kt * 32 + kg * 8);
        bs[g] = bfold[g * 128 + wv * 16 + un];
    }
    // proj A-frags (waves 4..7 use them; mt=wv&3 keeps addresses valid)
    const int mt = wv & 3;
    f16x8 wo[4];
#pragma unroll
    for (int kt = 0; kt < 4; ++kt) {
        const float* src = Wout + (size_t)(mt * 16 + n16) * Hq + kt * 32 + kg * 8;
        float4 f0 = *(const float4*)src;
        float4 f1 = *(const float4*)(src + 4);
        f16x8 a;
        a[0] = (f16)f0.x; a[1] = (f16)f0.y; a[2] = (f16)f0.z; a[3] = (f16)f0.w;
        a[4] = (f16)f1.x; a[5] = (f16)f1.y; a[6] = (f16)f1.z; a[7] = (f16)f1.w;
        wo[kt] = a;
    }
    float4 bo4 = *(const float4*)(bout + mt * 16 + kg * 4);
    float4 tsv = *(const float4*)(ts + (size_t)(row0 + zr) * Tq * Fq +
                                  (size_t)(Tq - 1) * Fq + mt * 16 + kg * 4);
    float err_ = 0.f;
    __syncthreads();

    // ===================== decoder: 512 steps, 1 barrier each ============
    for (int k = 0; k < Tq; ++k) {
        const int pk = k & 1;
        f16x8 bf[4];
#pragma unroll
        for (int kt = 0; kt < 4; ++kt)
            bf[kt] = *(const f16x8*)(&hT[pk][zr][kt * 32 + kg * 8]);
        f32x4 acc[4];
#pragma unroll
        for (int g = 0; g < 4; ++g) acc[g] = (f32x4){0.f, 0.f, 0.f, 0.f};
#pragma unroll
        for (int kt = 0; kt < 4; ++kt)
#pragma unroll
            for (int g = 0; g < 4; ++g)
                acc[g] = __builtin_amdgcn_mfma_f32_16x16x32_f16(
                    wc[g][kt], bf[kt], acc[g], 0, 0, 0);
        if (wv >= 4) {   // concurrent projection of h[pk] for rec_err
            f32x4 pacc = (f32x4){0.f, 0.f, 0.f, 0.f};
#pragma unroll
            for (int kt = 0; kt < 4; ++kt)
                pacc = __builtin_amdgcn_mfma_f32_16x16x32_f16(
                    wo[kt], bf[kt], pacc, 0, 0, 0);
            if (act) {
                float a0 = pacc[0] + bo4.x, a1 = pacc[1] + bo4.y;
                float a2 = pacc[2] + bo4.z, a3 = pacc[3] + bo4.w;
                if (k == 0) {
                    float4 av; av.x = a0; av.y = a1; av.z = a2; av.w = a3;
                    *(float4*)(out + (size_t)Bq * Hq + Bq +
                               (size_t)(row0 + n16) * Fq + mt * 16 + kg * 4) = av;
                }
                err_ += fabsf(a0 * a0 - tsv.x * tsv.x);
                err_ += fabsf(a1 * a1 - tsv.y * tsv.y);
                err_ += fabsf(a2 * a2 - tsv.z * tsv.z);
                err_ += fabsf(a3 * a3 - tsv.w * tsv.w);
                if (k < Tq - 1)
                    tsv = *(const float4*)(ts + (size_t)(row0 + n16) * Tq * Fq +
                                           (size_t)(Tq - 2 - k) * Fq +
                                           mt * 16 + kg * 4);
            }
        }
        {   // in-register pointwise
            float gi = sel4(acc[0], us) + bs[0];
            float gf = sel4(acc[1], us) + bs[1];
            float gg = sel4(acc[2], us) + bs[2];
            float go = sel4(acc[3], us) + bs[3];
            float i_ = sigmoidf_(gi);
            float f_ = sigmoidf_(gf);
            float g_ = tanhf_(gg);
            float o_ = sigmoidf_(go);
            c_ = f_ * c_ + i_ * g_;
            hT[pk ^ 1][zr][wv * 16 + un] = (f16)(o_ * tanhf_(c_));
        }
        __syncthreads();
    }

    // rec_err reduction: waves 4..7 hold per-(row,f-slice) partials
    if (wv >= 4) {
        err_ += __shfl_xor(err_, 16, 64);   // sum over kg bit 0
        err_ += __shfl_xor(err_, 32, 64);   // sum over kg bit 1
        if (kg == 0 && act) errb[mt][n16] = err_;
    }
    __syncthreads();
    if (tid < 4) {
        float e = errb[0][tid] + errb[1][tid] + errb[2][tid] + errb[3][tid];
        out[(size_t)Bq * Hq + row0 + tid] = e;
    }
}

extern "C" void kernel_launch(void* const* d_in, const int* in_sizes, int n_in,
                              void* d_out, int out_size, void* d_ws, size_t ws_size,
                              hipStream_t stream) {
    const float* ts    = (const float*)d_in[0];
    const float* Wih_e = (const float*)d_in[1];
    const float* Whh_e = (const float*)d_in[2];
    const float* bih_e = (const float*)d_in[3];
    const float* bhh_e = (const float*)d_in[4];
    const float* Wih_d = (const float*)d_in[5];
    const float* Whh_d = (const float*)d_in[6];
    const float* bih_d = (const float*)d_in[7];
    const float* bhh_d = (const float*)d_in[8];
    const float* Wout  = (const float*)d_in[9];
    const float* bout  = (const float*)d_in[10];
    float* out = (float*)d_out;

    f16*   Wcomb = (f16*)d_ws;                                   // 128 KB
    float* bfold = (float*)((char*)d_ws + (size_t)512 * 128 * 2); // +2 KB

    hipLaunchKernelGGL(fold_kernel, dim3(128), dim3(256), 0, stream,
                       Wih_d, Whh_d, bih_d, bhh_d, Wout, bout, Wcomb, bfold);
    hipLaunchKernelGGL(lstm_ae_kernel, dim3(Bq / 4), dim3(512), 0, stream,
                       ts, Wih_e, Whh_e, bih_e, bhh_e,
                       Wout, bout, Wcomb, bfold, out);
}